// Round 1
// baseline (362.529 us; speedup 1.0000x reference)
//
#include <hip/hip_runtime.h>
#include <hip/hip_bf16.h>

#define B_    2
#define NSEQ  2048
#define FDIM  1024
#define NH    16
#define HD    64
#define MTOT  (B_*NSEQ)   // 4096
#define ATT_SCALE 0.125f  // 64^-0.5

typedef __bf16 bf16_t;
typedef __bf16 bf16x4 __attribute__((ext_vector_type(4)));
typedef __bf16 bf16x8 __attribute__((ext_vector_type(8)));
typedef float  f32x4  __attribute__((ext_vector_type(4)));

#define AS1 __attribute__((address_space(1)))
#define AS3 __attribute__((address_space(3)))

__device__ __forceinline__ void gld_lds16(const bf16_t* g, bf16_t* l) {
  // async global->LDS, 16B per lane; LDS dest = wave-uniform base + lane*16
  __builtin_amdgcn_global_load_lds((const AS1 void*)g, (AS3 void*)l, 16, 0, 0);
}

// ---------------------------------------------------------------------------
// Kernel 1: fp32 -> bf16 casts for x, Wq, Wk, Wv, Wo (8,388,608 elems total)
// ---------------------------------------------------------------------------
extern "C" __global__ __launch_bounds__(256) void cast_all_k(
    const float* __restrict__ x,  const float* __restrict__ wq,
    const float* __restrict__ wk, const float* __restrict__ wv,
    const float* __restrict__ wo,
    bf16_t* __restrict__ xb,  bf16_t* __restrict__ wqb,
    bf16_t* __restrict__ wkb, bf16_t* __restrict__ wvb,
    bf16_t* __restrict__ wob)
{
  long t = (long)blockIdx.x * blockDim.x + threadIdx.x;
  long i = t * 4;
  const float* src; bf16_t* dst; long off;
  if      (i < 4194304L) { src = x;  dst = xb;  off = i; }
  else if (i < 5242880L) { src = wq; dst = wqb; off = i - 4194304L; }
  else if (i < 6291456L) { src = wk; dst = wkb; off = i - 5242880L; }
  else if (i < 7340032L) { src = wv; dst = wvb; off = i - 6291456L; }
  else                   { src = wo; dst = wob; off = i - 7340032L; }
  float4 v = *(const float4*)(src + off);
  bf16x4 o = { (bf16_t)v.x, (bf16_t)v.y, (bf16_t)v.z, (bf16_t)v.w };
  *(bf16x4*)(dst + off) = o;
}

// ---------------------------------------------------------------------------
// Kernel 2/4: bf16 GEMM out[m][n] = sum_k A[m][k]*W[n][k]  (nn.Linear x@W.T)
// 128x128 tile, BK=32, 4 waves of 64x64, global_load_lds staging.
// mode 0: write Q [b][h][tok][d]   mode 1: write K [b][h][tok][d]
// mode 2: write V transposed [b][h][d][tok]
// mode 3: write fp32 out [m][n] + bias[n]
// ---------------------------------------------------------------------------
extern "C" __global__ __launch_bounds__(256) void gemm_bt_k(
    const bf16_t* __restrict__ A,
    const bf16_t* __restrict__ Bq, const bf16_t* __restrict__ Bk,
    const bf16_t* __restrict__ Bv,
    bf16_t* __restrict__ oq, bf16_t* __restrict__ okk,
    bf16_t* __restrict__ ovt, float* __restrict__ oo,
    const float* __restrict__ bias, int mode_base)
{
  __shared__ __align__(16) bf16_t As[128*32];
  __shared__ __align__(16) bf16_t Bs[128*32];
  const int K = FDIM;
  int mode = mode_base + blockIdx.z;
  const bf16_t* Bw = (mode == 0) ? Bq : (mode == 1) ? Bk : (mode == 2) ? Bv : Bq;
  int m0 = blockIdx.y * 128, n0 = blockIdx.x * 128;
  int tid = threadIdx.x, lane = tid & 63, wave = tid >> 6;
  int g = lane >> 4, c = lane & 15;
  int wm = (wave >> 1) * 64, wn = (wave & 1) * 64;
  f32x4 acc[4][4];
  for (int i = 0; i < 4; ++i)
    for (int j = 0; j < 4; ++j)
      acc[i][j] = (f32x4){0.f, 0.f, 0.f, 0.f};

  int srow = lane >> 2;        // row within 16-row chunk
  int scol = (lane & 3) * 8;   // k-col within 32

  for (int kt = 0; kt < K / 32; ++kt) {
    int kk = kt * 32;
    for (int cc = 0; cc < 2; ++cc) {
      int chunk = wave * 2 + cc;              // 0..7, 16 rows each
      const bf16_t* ag = A  + (long)(m0 + chunk*16 + srow) * K + kk + scol;
      const bf16_t* bg = Bw + (long)(n0 + chunk*16 + srow) * K + kk + scol;
      gld_lds16(ag, As + chunk * 512);
      gld_lds16(bg, Bs + chunk * 512);
    }
    __syncthreads();
    bf16x8 af[4], bfr[4];
    for (int t = 0; t < 4; ++t) {
      af[t]  = *(const bf16x8*)(As + (wm + t*16 + c) * 32 + g * 8);
      bfr[t] = *(const bf16x8*)(Bs + (wn + t*16 + c) * 32 + g * 8);
    }
    for (int mt = 0; mt < 4; ++mt)
      for (int nt = 0; nt < 4; ++nt)
        acc[mt][nt] = __builtin_amdgcn_mfma_f32_16x16x32_bf16(
            af[mt], bfr[nt], acc[mt][nt], 0, 0, 0);
    __syncthreads();
  }

  // epilogue: C elem (mt,nt,r): row m = m0+wm+mt*16+g*4+r, col n = n0+wn+nt*16+c
  if (mode < 2) {
    bf16_t* dst = (mode == 0) ? oq : okk;
    for (int mt = 0; mt < 4; ++mt)
      for (int nt = 0; nt < 4; ++nt) {
        int n = n0 + wn + nt*16 + c;
        int h = n >> 6, d = n & 63;
        for (int r = 0; r < 4; ++r) {
          int m = m0 + wm + mt*16 + g*4 + r;
          int b = m >> 11, tok = m & 2047;
          dst[((long)(b*NH + h) * NSEQ + tok) * HD + d] = (bf16_t)acc[mt][nt][r];
        }
      }
  } else if (mode == 2) {
    for (int mt = 0; mt < 4; ++mt)
      for (int nt = 0; nt < 4; ++nt) {
        int n = n0 + wn + nt*16 + c;
        int h = n >> 6, d = n & 63;
        int m = m0 + wm + mt*16 + g*4;   // r=0..3 are consecutive toks
        int b = m >> 11, tok = m & 2047;
        bf16x4 pk = { (bf16_t)acc[mt][nt][0], (bf16_t)acc[mt][nt][1],
                      (bf16_t)acc[mt][nt][2], (bf16_t)acc[mt][nt][3] };
        *(bf16x4*)(ovt + ((long)(b*NH + h) * HD + d) * NSEQ + tok) = pk;
      }
  } else {
    for (int mt = 0; mt < 4; ++mt)
      for (int nt = 0; nt < 4; ++nt) {
        int n = n0 + wn + nt*16 + c;
        float bv = bias[n];
        for (int r = 0; r < 4; ++r) {
          int m = m0 + wm + mt*16 + g*4 + r;
          oo[(long)m * FDIM + n] = acc[mt][nt][r] + bv;
        }
      }
  }
}

// ---------------------------------------------------------------------------
// Kernel 3: flash attention. Block = 256 thr (4 waves), 128 q-rows/block
// (32 per wave). K-tiles of 64. Q/K/Vt frags loaded straight from global.
// P (C-layout) -> A-layout via per-wave LDS buffer, stride 72 (16B aligned).
// ---------------------------------------------------------------------------
extern "C" __global__ __launch_bounds__(256) void attn_fused_k(
    const bf16_t* __restrict__ q, const bf16_t* __restrict__ k,
    const bf16_t* __restrict__ vt, bf16_t* __restrict__ attn)
{
  __shared__ __align__(16) bf16_t Pl[4 * 32 * 72];
  int bh = blockIdx.y;                 // 0..31 = b*16+h
  int qb = blockIdx.x * 128;
  int tid = threadIdx.x, lane = tid & 63, wave = tid >> 6;
  int g = lane >> 4, c = lane & 15;
  const bf16_t* Q  = q  + (long)bh * NSEQ * HD;
  const bf16_t* Kp = k  + (long)bh * NSEQ * HD;
  const bf16_t* Vt = vt + (long)bh * HD * NSEQ;
  bf16_t* Pw = Pl + wave * (32 * 72);
  int qw = qb + wave * 32;

  bf16x8 aQ[2][2];
  for (int t = 0; t < 2; ++t)
    for (int kb = 0; kb < 2; ++kb)
      aQ[t][kb] = *(const bf16x8*)(Q + (long)(qw + t*16 + c) * HD + kb*32 + g*8);

  f32x4 acc[2][4];
  for (int t = 0; t < 2; ++t)
    for (int jt = 0; jt < 4; ++jt)
      acc[t][jt] = (f32x4){0.f, 0.f, 0.f, 0.f};
  float mrun[2][4], lrun[2][4];
  for (int t = 0; t < 2; ++t)
    for (int r = 0; r < 4; ++r) { mrun[t][r] = -1e30f; lrun[t][r] = 0.f; }

  for (int kt = 0; kt < NSEQ / 64; ++kt) {
    int k0 = kt * 64;
    // S = Q K^T (scaled)
    f32x4 s[2][4];
    for (int nt = 0; nt < 4; ++nt) {
      bf16x8 bK0 = *(const bf16x8*)(Kp + (long)(k0 + nt*16 + c) * HD + g*8);
      bf16x8 bK1 = *(const bf16x8*)(Kp + (long)(k0 + nt*16 + c) * HD + 32 + g*8);
      for (int t = 0; t < 2; ++t) {
        f32x4 z = (f32x4){0.f, 0.f, 0.f, 0.f};
        z = __builtin_amdgcn_mfma_f32_16x16x32_bf16(aQ[t][0], bK0, z, 0, 0, 0);
        z = __builtin_amdgcn_mfma_f32_16x16x32_bf16(aQ[t][1], bK1, z, 0, 0, 0);
        s[t][nt] = z;
      }
    }
    for (int t = 0; t < 2; ++t)
      for (int nt = 0; nt < 4; ++nt)
        s[t][nt] *= ATT_SCALE;

    // online softmax: C-row x lives in lanes (x>>2)*16..+15, reg x&3
    float alpha[2][4];
    for (int t = 0; t < 2; ++t)
      for (int r = 0; r < 4; ++r) {
        float mx = fmaxf(fmaxf(s[t][0][r], s[t][1][r]),
                         fmaxf(s[t][2][r], s[t][3][r]));
        for (int off = 1; off < 16; off <<= 1)
          mx = fmaxf(mx, __shfl_xor(mx, off));
        float mnew = fmaxf(mrun[t][r], mx);
        alpha[t][r] = __expf(mrun[t][r] - mnew);
        mrun[t][r] = mnew;
        float rs = 0.f;
        for (int nt = 0; nt < 4; ++nt) {
          float p = __expf(s[t][nt][r] - mnew);
          s[t][nt][r] = p;
          rs += p;
        }
        for (int off = 1; off < 16; off <<= 1)
          rs += __shfl_xor(rs, off);
        lrun[t][r] = lrun[t][r] * alpha[t][r] + rs;
      }
    for (int t = 0; t < 2; ++t)
      for (int jt = 0; jt < 4; ++jt)
        for (int r = 0; r < 4; ++r)
          acc[t][jt][r] *= alpha[t][r];

    // P: C-layout -> LDS [row][col], stride 72
    for (int t = 0; t < 2; ++t)
      for (int nt = 0; nt < 4; ++nt)
        for (int r = 0; r < 4; ++r)
          Pw[(t*16 + g*4 + r) * 72 + nt*16 + c] = (bf16_t)s[t][nt][r];
    __syncthreads();

    // O += P V  : A = P (A-layout from LDS), B = V[k][d] = Vt[d][k]
    for (int step = 0; step < 2; ++step) {
      bf16x8 aP[2];
      for (int t = 0; t < 2; ++t)
        aP[t] = *(const bf16x8*)(Pw + (t*16 + c) * 72 + step*32 + g*8);
      for (int jt = 0; jt < 4; ++jt) {
        bf16x8 bV = *(const bf16x8*)(Vt + (long)(jt*16 + c) * NSEQ
                                     + k0 + step*32 + g*8);
        for (int t = 0; t < 2; ++t)
          acc[t][jt] = __builtin_amdgcn_mfma_f32_16x16x32_bf16(
              aP[t], bV, acc[t][jt], 0, 0, 0);
      }
    }
    __syncthreads();
  }

  // epilogue: O = acc / l, write [b][tok][h*64+d] bf16
  int b = bh >> 4, h = bh & 15;
  for (int t = 0; t < 2; ++t)
    for (int r = 0; r < 4; ++r) {
      float inv = 1.f / lrun[t][r];
      int tok = qw + t*16 + g*4 + r;
      bf16_t* dst = attn + ((long)(b * NSEQ + tok)) * FDIM + h * HD;
      for (int jt = 0; jt < 4; ++jt)
        dst[jt*16 + c] = (bf16_t)(acc[t][jt][r] * inv);
    }
}

// ---------------------------------------------------------------------------
extern "C" void kernel_launch(void* const* d_in, const int* in_sizes, int n_in,
                              void* d_out, int out_size, void* d_ws, size_t ws_size,
                              hipStream_t stream)
{
  const float* x  = (const float*)d_in[0];
  const float* wq = (const float*)d_in[1];
  const float* wk = (const float*)d_in[2];
  const float* wv = (const float*)d_in[3];
  const float* wo = (const float*)d_in[4];
  const float* bo = (const float*)d_in[5];
  float* out = (float*)d_out;
  char* ws = (char*)d_ws;

  const size_t MB = 1024 * 1024;
  bf16_t* xb    = (bf16_t*)(ws);              //  8 MB: x bf16 [4096][1024]
  bf16_t* wqb   = (bf16_t*)(ws + 8  * MB);    //  2 MB
  bf16_t* wkb   = (bf16_t*)(ws + 10 * MB);    //  2 MB
  bf16_t* wvb   = (bf16_t*)(ws + 12 * MB);    //  2 MB
  bf16_t* wob   = (bf16_t*)(ws + 14 * MB);    //  2 MB
  bf16_t* q_ws  = (bf16_t*)(ws + 16 * MB);    //  8 MB: [bh][tok][d]
  bf16_t* k_ws  = (bf16_t*)(ws + 24 * MB);    //  8 MB: [bh][tok][d]
  bf16_t* vt_ws = (bf16_t*)(ws + 32 * MB);    //  8 MB: [bh][d][tok]
  bf16_t* at_ws = (bf16_t*)(ws + 40 * MB);    //  8 MB: [b*tok][1024]

  hipLaunchKernelGGL(cast_all_k, dim3(8192), dim3(256), 0, stream,
                     x, wq, wk, wv, wo, xb, wqb, wkb, wvb, wob);

  hipLaunchKernelGGL(gemm_bt_k, dim3(8, 32, 3), dim3(256), 0, stream,
                     xb, wqb, wkb, wvb, q_ws, k_ws, vt_ws,
                     (float*)nullptr, (const float*)nullptr, 0);

  hipLaunchKernelGGL(attn_fused_k, dim3(16, 32), dim3(256), 0, stream,
                     q_ws, k_ws, vt_ws, at_ws);

  hipLaunchKernelGGL(gemm_bt_k, dim3(8, 32, 1), dim3(256), 0, stream,
                     at_ws, wob, wob, wob,
                     (bf16_t*)nullptr, (bf16_t*)nullptr, (bf16_t*)nullptr,
                     out, bo, 3);
}